// Round 6
// baseline (25426.936 us; speedup 1.0000x reference)
//
#include <hip/hip_runtime.h>

#define T_STEPS 8192
#define HID 256
#define NBLK 128      // dispatched; 16 co-located on one elected XCD participate
#define THREADS 256   // 4 waves, each a self-sufficient scan agent
#define CAP_T0  16384 // t==0 fast-poll budget (startup skew)
#define CAP_RUN 24    // t>0 fast-poll rounds before per-step fallback
#define FB_CAP  256   // cumulative fallbacks before sticky demotion (R3 lesson)

#define MAGIC_READY 0x13579BDFu
#define EMPTY_XCD   0xFFFFFFFFu
#define DONE_MAGIC  0x600DD00Eu

typedef float v4f __attribute__((ext_vector_type(4)));

// 2/(1+e^-2x)-1 is inf-safe at both ends
__device__ __forceinline__ float tanh_fast(float x) { return 2.0f / (1.0f + __expf(-2.0f * x)) - 1.0f; }

// ---- order-pinned issue helpers (volatile asm preserves program order) ----
// emb row slice: one dwordx4 per lane (cached path is fine; row reused 0 times, L2/MALL-served)
__device__ __forceinline__ void ld_e_issue(const float* p, v4f& e) {
    asm volatile("global_load_dwordx4 %0, %1, off" : "=v"(e) : "v"(p) : "memory");
}
__device__ __forceinline__ void ld_tok_issue(const int* p, int& t) {
    asm volatile("global_load_dword %0, %1, off" : "=v"(t) : "v"(p) : "memory");
}
// poll batch: 4x8B agent-scope (sc1) loads — R2-proven delivery flavor
__device__ __forceinline__ void ld4_issue_sc1(const unsigned long long* p,
                                              unsigned long long& a, unsigned long long& b,
                                              unsigned long long& c, unsigned long long& d) {
    asm volatile(
        "global_load_dwordx2 %0, %4, off sc1\n\t"
        "global_load_dwordx2 %1, %4, off offset:8 sc1\n\t"
        "global_load_dwordx2 %2, %4, off offset:16 sc1\n\t"
        "global_load_dwordx2 %3, %4, off offset:24 sc1"
        : "=&v"(a), "=&v"(b), "=&v"(c), "=&v"(d)
        : "v"(p) : "memory");
}
// waits + dataflow-bind (rule-18: "memory" alone doesn't order register reads of asm outputs)
__device__ __forceinline__ void vm_wait0_bind_all(unsigned long long& a, unsigned long long& b,
                                                  unsigned long long& c, unsigned long long& d,
                                                  v4f& e, int& tk) {
    asm volatile("s_waitcnt vmcnt(0)" ::: "memory");
    __builtin_amdgcn_sched_barrier(0);
    asm volatile("" : "+v"(a), "+v"(b), "+v"(c), "+v"(d), "+v"(e), "+v"(tk));
}
__device__ __forceinline__ void vm_wait4_bind(unsigned long long& a, unsigned long long& b,
                                              unsigned long long& c, unsigned long long& d) {
    asm volatile("s_waitcnt vmcnt(4)" ::: "memory");   // 4 newest ops (other batch) keep flying
    __builtin_amdgcn_sched_barrier(0);
    asm volatile("" : "+v"(a), "+v"(b), "+v"(c), "+v"(d));
}
__device__ __forceinline__ bool tags_ok(unsigned long long a, unsigned long long b,
                                        unsigned long long c, unsigned long long d, unsigned tt) {
    return ((unsigned)(a >> 32) == tt) & ((unsigned)(b >> 32) == tt) &
           ((unsigned)(c >> 32) == tt) & ((unsigned)(d >> 32) == tt);
}

__global__ __launch_bounds__(THREADS, 1)
void lstm_scan(const int* __restrict__ tokens,
               const float* __restrict__ emb,    // [V,256] fp32
               const float* __restrict__ Wih,    // [1024,256] fp32
               const float* __restrict__ Whh,    // [1024,256] fp32
               const float* __restrict__ bih,    // [1024]
               const float* __restrict__ bhh,    // [1024]
               float* __restrict__ out,          // [T*256 + 256 + 256] fp32
               unsigned long long* __restrict__ hbL,   // ws+0: unused this round (ABI keep)
               unsigned long long* __restrict__ hbA,   // ws+4096: [2][256] agent exchange buffer
               unsigned* __restrict__ ctl)             // ws+8192: ready, elected, cnt[8], done
{
    (void)hbL;
    // ---- XCD election: find 16 blocks co-located on one XCD (pigeonhole over 128) ----
    __shared__ int s_role;
    if (threadIdx.x == 0) {
        unsigned xcc;
        asm volatile("s_getreg_b32 %0, hwreg(HW_REG_XCC_ID, 0, 4)" : "=s"(xcc));
        unsigned* ready   = ctl + 0;
        unsigned* elected = ctl + 1;
        unsigned* cnt     = ctl + 2;   // [8]
        if (blockIdx.x == 0) {
            for (int i = 0; i < 8; ++i)
                __hip_atomic_store(cnt + i, 0u, __ATOMIC_RELAXED, __HIP_MEMORY_SCOPE_AGENT);
            __hip_atomic_store(elected, EMPTY_XCD, __ATOMIC_RELAXED, __HIP_MEMORY_SCOPE_AGENT);
            __hip_atomic_store(ctl + 10, 0u, __ATOMIC_RELAXED, __HIP_MEMORY_SCOPE_AGENT); // done
            __hip_atomic_store(ready, MAGIC_READY, __ATOMIC_RELEASE, __HIP_MEMORY_SCOPE_AGENT);
        }
        while (__hip_atomic_load(ready, __ATOMIC_ACQUIRE, __HIP_MEMORY_SCOPE_AGENT) != MAGIC_READY)
            asm volatile("s_sleep 1");
        unsigned r = __hip_atomic_fetch_add(cnt + xcc, 1u, __ATOMIC_RELAXED, __HIP_MEMORY_SCOPE_AGENT);
        if (r == 15u) {   // 16th arrival on this XCD: claim election (guaranteed to occur)
            unsigned expv = EMPTY_XCD;
            __hip_atomic_compare_exchange_strong(elected, &expv, xcc,
                __ATOMIC_RELAXED, __ATOMIC_RELAXED, __HIP_MEMORY_SCOPE_AGENT);
        }
        unsigned e;
        while ((e = __hip_atomic_load(elected, __ATOMIC_ACQUIRE, __HIP_MEMORY_SCOPE_AGENT)) == EMPTY_XCD)
            asm volatile("s_sleep 1");
        s_role = (xcc == e && r < 16u) ? (int)r : -1;
    }
    __syncthreads();
    const int w = s_role;          // role 0..15, or -1 = anti-DVFS spinner

    if (w < 0) {
        // Bystanders keep the clock governor awake with pure-register VALU work.
        float x0 = 1.0f, x1 = 2.0f, x2 = 3.0f, x3 = 4.0f;
        const float a = 1.0000001f, b = 1e-7f;
        const unsigned* done = ctl + 10;
        for (;;) {
            #pragma unroll 64
            for (int i = 0; i < 512; ++i) {
                x0 = fmaf(x0, a, b); x1 = fmaf(x1, a, b);
                x2 = fmaf(x2, a, b); x3 = fmaf(x3, a, b);
            }
            if (__hip_atomic_load(done, __ATOMIC_RELAXED, __HIP_MEMORY_SCOPE_AGENT) == DONE_MAGIC)
                break;
        }
        asm volatile("" :: "v"(x0 + x1 + x2 + x3));
        return;
    }

    // ---- WAVE-AUTONOMOUS scan: no barriers in the loop. Each wave polls all 256 h
    // itself, redistributes via wave-private LDS (lgkmcnt only), loads its own emb
    // row, computes its 16 gate-rows, owners publish to the agent buffer. ----
    const int tid  = threadIdx.x;
    const int lane = tid & 63;
    const int wave = tid >> 6;         // 0..3
    const int rl   = lane >> 2;        // row-within-wave 0..15
    const int kq   = lane & 3;         // k-quarter 0..3
    const int r_wg = wave * 16 + rl;   // local gate-row 0..63
    const int unit_local = r_wg >> 2;  // 0..15
    const int gate = r_wg & 3;         // 0=i 1=f 2=cell 3=o
    const int unit = w * 16 + unit_local;      // global hidden unit 0..255
    const int grow = gate * 256 + unit;        // global gate row 0..1023
    const int kbase = kq * 64;

    float whh[64], wih[64];
    {
        const float* p = Whh + (size_t)grow * 256 + kbase;
        #pragma unroll
        for (int j = 0; j < 64; j += 4) {
            float4 q = *(const float4*)(p + j);
            whh[j] = q.x; whh[j+1] = q.y; whh[j+2] = q.z; whh[j+3] = q.w;
        }
        p = Wih + (size_t)grow * 256 + kbase;
        #pragma unroll
        for (int j = 0; j < 64; j += 4) {
            float4 q = *(const float4*)(p + j);
            wih[j] = q.x; wih[j+1] = q.y; wih[j+2] = q.z; wih[j+3] = q.w;
        }
    }
    const float bias = bih[grow] + bhh[grow];
    const bool owner = ((lane & 15) == 0);             // 4 owners per wave
    const float act_scale = (gate == 2) ? 2.0f : 1.0f; // tanh vs sigmoid, single-exp form
    const float act_off   = (gate == 2) ? 1.0f : 0.0f;

    // wave-private LDS: no cross-wave sharing at all -> no barriers needed
    __shared__ v4f lds_h[4][4][17];       // [wave][kq][16+pad]
    __shared__ v4f lds_e[4][2][4][17];    // [wave][parity][kq][16+pad]

    // publish h=0 with tag 0 into parity-0 (stale tags from prior dispatch never match)
    if (owner)
        __hip_atomic_store(hbA + unit, 0ull, __ATOMIC_RELAXED, __HIP_MEMORY_SCOPE_AGENT);
    // prologue: emb row for t=0 into parity 0; tok_n = tokens[1]
    {
        int tk0 = tokens[0];
        v4f e0 = *(const v4f*)(emb + (size_t)tk0 * 256 + lane * 4);
        lds_e[wave][0][lane >> 4][lane & 15] = e0;
    }
    int tok_n = tokens[1];
    float c = 0.0f;
    bool useFast = true;   // sticky demotion flag (per-wave)
    int  fb_used = 0;
    asm volatile("s_waitcnt vmcnt(0)" ::: "memory");   // init publish committed outbound

    for (int t = 0; t < T_STEPS; ++t) {
        const unsigned int tt = (unsigned int)t;
        // -- order-pinned issues: emb(t+1), tokens(t+2), poll batch A --
        const float* ep = emb + (size_t)tok_n * 256 + lane * 4;
        const int*   kp = tokens + ((t + 2 < T_STEPS) ? t + 2 : T_STEPS - 1);
        unsigned long long* hbp = hbA + (size_t)(t & 1) * 256 + lane * 4;
        v4f ev; int tk2 = 0;
        unsigned long long a0 = 0, a1 = 0, a2 = 0, a3 = 0;
        ld_e_issue(ep, ev);
        ld_tok_issue(kp, tk2);
        if (useFast) ld4_issue_sc1(hbp, a0, a1, a2, a3);

        // input contribution while everything flies: wih . emb_t, 4 chains
        float aA = 0.0f, aB = 0.0f, aC = 0.0f, aD = 0.0f;
        {
            const v4f* eb = &lds_e[wave][t & 1][kq][0];
            #pragma unroll
            for (int i = 0; i < 16; i += 4) {
                v4f v0 = eb[i], v1 = eb[i+1], v2 = eb[i+2], v3 = eb[i+3];
                aA = fmaf(wih[4*i+ 0], v0[0], aA); aA = fmaf(wih[4*i+ 1], v0[1], aA);
                aA = fmaf(wih[4*i+ 2], v0[2], aA); aA = fmaf(wih[4*i+ 3], v0[3], aA);
                aB = fmaf(wih[4*i+ 4], v1[0], aB); aB = fmaf(wih[4*i+ 5], v1[1], aB);
                aB = fmaf(wih[4*i+ 6], v1[2], aB); aB = fmaf(wih[4*i+ 7], v1[3], aB);
                aC = fmaf(wih[4*i+ 8], v2[0], aC); aC = fmaf(wih[4*i+ 9], v2[1], aC);
                aC = fmaf(wih[4*i+10], v2[2], aC); aC = fmaf(wih[4*i+11], v2[3], aC);
                aD = fmaf(wih[4*i+12], v3[0], aD); aD = fmaf(wih[4*i+13], v3[1], aD);
                aD = fmaf(wih[4*i+14], v3[2], aD); aD = fmaf(wih[4*i+15], v3[3], aD);
            }
        }
        // drain: emb+tok+batchA all retired (equal flight times; nothing newer gates)
        vm_wait0_bind_all(a0, a1, a2, a3, ev, tk2);
        lds_e[wave][(t + 1) & 1][lane >> 4][lane & 15] = ev;   // stage next emb row
        tok_n = tk2;

        // -- acquire this step's 4 (h,tag) pairs --
        unsigned long long r0 = a0, r1 = a1, r2 = a2, r3 = a3;
        bool got = useFast && tags_ok(a0, a1, a2, a3, tt);
        if (useFast && !got) {
            // staggered ping-pong: sample the line every ~RTT/2 instead of every RTT
            unsigned long long b0, b1, b2, b3;
            ld4_issue_sc1(hbp, b0, b1, b2, b3);
            const int cap = (t == 0) ? CAP_T0 : CAP_RUN;
            int n = 0;
            for (;;) {
                ld4_issue_sc1(hbp, a0, a1, a2, a3);     // A flies while we check B
                vm_wait4_bind(b0, b1, b2, b3);
                if (tags_ok(b0, b1, b2, b3, tt)) { r0 = b0; r1 = b1; r2 = b2; r3 = b3; got = true; break; }
                if (++n > cap) break;
                ld4_issue_sc1(hbp, b0, b1, b2, b3);     // B flies while we check A
                vm_wait4_bind(a0, a1, a2, a3);
                if (tags_ok(a0, a1, a2, a3, tt)) { r0 = a0; r1 = a1; r2 = a2; r3 = a3; got = true; break; }
                if (++n > cap) break;
            }
            if (!got && ++fb_used > FB_CAP) useFast = false;   // fast path is a net loss
        }
        if (!got) {
            // proven agent channel (baseline formulation) — unbounded, delivery-proven
            const unsigned long long* ha = hbp;
            for (;;) {
                r0 = __hip_atomic_load(ha + 0, __ATOMIC_RELAXED, __HIP_MEMORY_SCOPE_AGENT);
                r1 = __hip_atomic_load(ha + 1, __ATOMIC_RELAXED, __HIP_MEMORY_SCOPE_AGENT);
                r2 = __hip_atomic_load(ha + 2, __ATOMIC_RELAXED, __HIP_MEMORY_SCOPE_AGENT);
                r3 = __hip_atomic_load(ha + 3, __ATOMIC_RELAXED, __HIP_MEMORY_SCOPE_AGENT);
                if (tags_ok(r0, r1, r2, r3, tt)) break;
            }
        }
        // redistribute through wave-private LDS (intra-wave: lgkmcnt ordering only)
        {
            union { unsigned int i; float f; } ua, ub, uc, ud;
            ua.i = (unsigned int)r0; ub.i = (unsigned int)r1;
            uc.i = (unsigned int)r2; ud.i = (unsigned int)r3;
            v4f hv; hv[0] = ua.f; hv[1] = ub.f; hv[2] = uc.f; hv[3] = ud.f;
            lds_h[wave][lane >> 4][lane & 15] = hv;
        }
        // recurrent contribution: whh . h — 4 chains (compiler inserts the lgkmcnt)
        {
            const v4f* hq = &lds_h[wave][kq][0];
            #pragma unroll
            for (int i = 0; i < 16; i += 4) {
                v4f v0 = hq[i], v1 = hq[i+1], v2 = hq[i+2], v3 = hq[i+3];
                aA = fmaf(whh[4*i+ 0], v0[0], aA); aA = fmaf(whh[4*i+ 1], v0[1], aA);
                aA = fmaf(whh[4*i+ 2], v0[2], aA); aA = fmaf(whh[4*i+ 3], v0[3], aA);
                aB = fmaf(whh[4*i+ 4], v1[0], aB); aB = fmaf(whh[4*i+ 5], v1[1], aB);
                aB = fmaf(whh[4*i+ 6], v1[2], aB); aB = fmaf(whh[4*i+ 7], v1[3], aB);
                aC = fmaf(whh[4*i+ 8], v2[0], aC); aC = fmaf(whh[4*i+ 9], v2[1], aC);
                aC = fmaf(whh[4*i+10], v2[2], aC); aC = fmaf(whh[4*i+11], v2[3], aC);
                aD = fmaf(whh[4*i+12], v3[0], aD); aD = fmaf(whh[4*i+13], v3[1], aD);
                aD = fmaf(whh[4*i+14], v3[2], aD); aD = fmaf(whh[4*i+15], v3[3], aD);
            }
        }
        float acc = (aA + aB) + (aC + aD);
        // butterfly reduce across the 4 k-quarter lanes
        acc += __shfl_xor(acc, 1, 64);
        acc += __shfl_xor(acc, 2, 64);
        acc += bias;
        // per-gate nonlinearity applied IN PARALLEL before the gather
        float ex = __expf(-act_scale * acc);
        float av = act_scale / (1.0f + ex) - act_off;  // sigm for gates 0/1/3, tanh for 2
        const int base = lane & 48;
        float fv = __shfl(av, base + 4,  64);
        float gv = __shfl(av, base + 8,  64);
        float ov = __shfl(av, base + 12, 64);
        if (owner) {
            c = fmaf(fv, c, av * gv);                  // av == i-gate on owner lanes
            float h_out = ov * tanh_fast(c);           // single serial transcendental
            union { unsigned int i; float f; } u; u.f = h_out;
            unsigned long long pk =
                (((unsigned long long)(unsigned int)(t + 1)) << 32) | (unsigned long long)u.i;
            __hip_atomic_store(hbA + (size_t)((t + 1) & 1) * 256 + unit, pk,
                               __ATOMIC_RELAXED, __HIP_MEMORY_SCOPE_AGENT);  // publish FIRST
            out[(size_t)t * HID + unit] = h_out;
            if (t == T_STEPS - 1) {
                out[(size_t)T_STEPS * HID + unit]       = h_out;  // h_last
                out[(size_t)T_STEPS * HID + HID + unit] = c;      // c_last
            }
        }
        // no drains: publish is older than next iter's poll batch and acks in parallel;
        // in-order vmcnt retire means it never adds latency to the next vmcnt wait.
    }

    if (w == 0 && tid == 0) {
        // release the anti-DVFS spinners, then re-arm the election protocol
        __hip_atomic_store(ctl + 10, DONE_MAGIC, __ATOMIC_RELEASE, __HIP_MEMORY_SCOPE_AGENT);
        __hip_atomic_store(ctl + 0, 0u, __ATOMIC_RELAXED, __HIP_MEMORY_SCOPE_AGENT);
    }
}

extern "C" void kernel_launch(void* const* d_in, const int* in_sizes, int n_in,
                              void* d_out, int out_size, void* d_ws, size_t ws_size,
                              hipStream_t stream) {
    const int*   tokens = (const int*)d_in[0];
    const float* emb    = (const float*)d_in[1];
    const float* Wih    = (const float*)d_in[2];
    const float* Whh    = (const float*)d_in[3];
    const float* bih    = (const float*)d_in[4];
    const float* bhh    = (const float*)d_in[5];
    float* out = (float*)d_out;
    unsigned long long* hbL = (unsigned long long*)d_ws;                    // unused (ABI keep)
    unsigned long long* hbA = (unsigned long long*)((char*)d_ws + 4096);    // [2][256] u64
    unsigned* ctl = (unsigned*)((char*)d_ws + 8192);                        // ready, elected, cnt[8], done

    lstm_scan<<<NBLK, THREADS, 0, stream>>>(tokens, emb, Wih, Whh, bih, bhh, out, hbL, hbA, ctl);
}

// Round 8
// 16847.328 us; speedup vs baseline: 1.5093x; 1.5093x over previous
//
#include <hip/hip_runtime.h>

#define T_STEPS 8192
#define HID 256
#define NBLK 128       // dispatched; 16 co-located on one elected XCD participate
#define THREADS 320    // 5 waves: 0-3 = compute (R0-proven math), 4 = STORE-FREE poller
#define SPIN_T0  16384 // t==0 poll budget (startup skew)
#define SPIN_RUN 64    // t>0 poll rounds before per-step fallback (~9us)
#define SLOW_N   8     // a step needing >SLOW_N rounds counts as "slow"
#define SLOW_CAP 512   // cumulative slow steps -> demote L2 path (R3 lesson)
#define FB_CAP   256   // cumulative fallbacks -> sticky demotion

#define MAGIC_READY 0x13579BDFu
#define EMPTY_XCD   0xFFFFFFFFu
#define DONE_MAGIC  0x600DD00Eu

typedef float v4f __attribute__((ext_vector_type(4)));

// 2/(1+e^-2x)-1 is inf-safe at both ends
__device__ __forceinline__ float tanh_fast(float x) { return 2.0f / (1.0f + __expf(-2.0f * x)) - 1.0f; }

// sc0 store: commit toward the XCD-local L2 (R5-passed producer flavor).
__device__ __forceinline__ void st_u64_sc0(unsigned long long* p, unsigned long long v) {
    asm volatile("global_store_dwordx2 %0, %1, off sc0" :: "v"(p), "v"(v) : "memory");
}
// Invalidate the CU's (write-through) vector L1 so sc0 loads re-probe the L2.
__device__ __forceinline__ void inv_l1() { asm volatile("buffer_inv sc0" ::: "memory"); }
__device__ __forceinline__ void ld4_issue_sc0(const unsigned long long* p,
                                              unsigned long long& a, unsigned long long& b,
                                              unsigned long long& c, unsigned long long& d) {
    asm volatile(
        "global_load_dwordx2 %0, %4, off sc0\n\t"
        "global_load_dwordx2 %1, %4, off offset:8 sc0\n\t"
        "global_load_dwordx2 %2, %4, off offset:16 sc0\n\t"
        "global_load_dwordx2 %3, %4, off offset:24 sc0"
        : "=&v"(a), "=&v"(b), "=&v"(c), "=&v"(d)
        : "v"(p) : "memory");
}
// THE POINT OF R8: this wait sits in a wave whose queue holds ONLY the 4 poll
// loads -> vmcnt(0) = pure load RTT, never a store ack (in-order retire poison).
// (rule-18: "memory" alone doesn't order register reads of asm outputs -> bind.)
__device__ __forceinline__ void vm_wait0_bind(unsigned long long& a, unsigned long long& b,
                                              unsigned long long& c, unsigned long long& d) {
    asm volatile("s_waitcnt vmcnt(0)" ::: "memory");
    __builtin_amdgcn_sched_barrier(0);
    asm volatile("" : "+v"(a), "+v"(b), "+v"(c), "+v"(d));
}
__device__ __forceinline__ void ld_e4_issue(const float* p, v4f& e) {
    asm volatile("global_load_dwordx4 %0, %1, off" : "=v"(e) : "v"(p) : "memory");
}
__device__ __forceinline__ bool tags_ok(unsigned long long a, unsigned long long b,
                                        unsigned long long c, unsigned long long d, unsigned tt) {
    return ((unsigned)(a >> 32) == tt) & ((unsigned)(b >> 32) == tt) &
           ((unsigned)(c >> 32) == tt) & ((unsigned)(d >> 32) == tt);
}

__global__ __launch_bounds__(THREADS, 1)
void lstm_scan(const int* __restrict__ tokens,
               const float* __restrict__ emb,    // [V,256] fp32
               const float* __restrict__ Wih,    // [1024,256] fp32
               const float* __restrict__ Whh,    // [1024,256] fp32
               const float* __restrict__ bih,    // [1024]
               const float* __restrict__ bhh,    // [1024]
               float* __restrict__ out,          // [T*256 + 256 + 256] fp32
               unsigned long long* __restrict__ hbL,   // ws+0:    [2][256] local-L2 channel
               unsigned long long* __restrict__ hbA,   // ws+4096: [2][256] agent fallback
               unsigned* __restrict__ ctl)             // ws+8192: ready, elected, cnt[8], done
{
    // ---- XCD election: find 16 blocks co-located on one XCD (pigeonhole over 128) ----
    __shared__ int s_role;
    if (threadIdx.x == 0) {
        unsigned xcc;
        asm volatile("s_getreg_b32 %0, hwreg(HW_REG_XCC_ID, 0, 4)" : "=s"(xcc));
        unsigned* ready   = ctl + 0;
        unsigned* elected = ctl + 1;
        unsigned* cnt     = ctl + 2;   // [8]
        if (blockIdx.x == 0) {
            for (int i = 0; i < 8; ++i)
                __hip_atomic_store(cnt + i, 0u, __ATOMIC_RELAXED, __HIP_MEMORY_SCOPE_AGENT);
            __hip_atomic_store(elected, EMPTY_XCD, __ATOMIC_RELAXED, __HIP_MEMORY_SCOPE_AGENT);
            __hip_atomic_store(ctl + 10, 0u, __ATOMIC_RELAXED, __HIP_MEMORY_SCOPE_AGENT); // done
            __hip_atomic_store(ready, MAGIC_READY, __ATOMIC_RELEASE, __HIP_MEMORY_SCOPE_AGENT);
        }
        while (__hip_atomic_load(ready, __ATOMIC_ACQUIRE, __HIP_MEMORY_SCOPE_AGENT) != MAGIC_READY)
            asm volatile("s_sleep 1");
        unsigned r = __hip_atomic_fetch_add(cnt + xcc, 1u, __ATOMIC_RELAXED, __HIP_MEMORY_SCOPE_AGENT);
        if (r == 15u) {
            unsigned expv = EMPTY_XCD;
            __hip_atomic_compare_exchange_strong(elected, &expv, xcc,
                __ATOMIC_RELAXED, __ATOMIC_RELAXED, __HIP_MEMORY_SCOPE_AGENT);
        }
        unsigned e;
        while ((e = __hip_atomic_load(elected, __ATOMIC_ACQUIRE, __HIP_MEMORY_SCOPE_AGENT)) == EMPTY_XCD)
            asm volatile("s_sleep 1");
        s_role = (xcc == e && r < 16u) ? (int)r : -1;
    }
    __syncthreads();
    const int w = s_role;          // role 0..15, or -1 = anti-DVFS spinner

    if (w < 0) {
        // Bystanders keep the clock governor awake with pure-register VALU work.
        float x0 = 1.0f, x1 = 2.0f, x2 = 3.0f, x3 = 4.0f;
        const float a = 1.0000001f, b = 1e-7f;
        const unsigned* done = ctl + 10;
        for (;;) {
            #pragma unroll 64
            for (int i = 0; i < 512; ++i) {
                x0 = fmaf(x0, a, b); x1 = fmaf(x1, a, b);
                x2 = fmaf(x2, a, b); x3 = fmaf(x3, a, b);
            }
            if (__hip_atomic_load(done, __ATOMIC_RELAXED, __HIP_MEMORY_SCOPE_AGENT) == DONE_MAGIC)
                break;
        }
        asm volatile("" :: "v"(x0 + x1 + x2 + x3));
        return;
    }

    const int tid  = threadIdx.x;
    const int lane = tid & 63;
    const int wave = tid >> 6;     // 0..3 compute; 4 = poller

    __shared__ v4f lds_h[2][4][17];                    // h parity double-buffer
    __shared__ v4f lds_e[2][4][17];                    // emb parity double-buffer
    __shared__ __align__(16) int s_tok[T_STEPS];       // 32KB: token lookup off vmcnt

    // cooperative token preload (once)
    for (int i = tid; i < T_STEPS / 4; i += THREADS)
        *(int4*)&s_tok[i * 4] = *(const int4*)&tokens[i * 4];
    __syncthreads();   // s_tok valid

    if (wave == 4) {
        __syncthreads();   // pairs with compute prologue-staging barrier
        // ================= STORE-FREE POLLER =================
        bool useL2 = true; int slow = 0, fb = 0;
        for (int t = 0; t < T_STEPS; ++t) {
            const unsigned tt = (unsigned)t;
            unsigned long long* hbp = hbL + (size_t)(t & 1) * 256 + lane * 4;
            unsigned long long q0, q1, q2, q3;
            bool got = false;
            if (useL2) {
                const int smax = (t == 0) ? SPIN_T0 : SPIN_RUN;
                int n = 0;
                for (;;) {
                    inv_l1();
                    ld4_issue_sc0(hbp, q0, q1, q2, q3);
                    vm_wait0_bind(q0, q1, q2, q3);     // PURE load RTT: queue has no stores
                    if (tags_ok(q0, q1, q2, q3, tt)) { got = true; break; }
                    if (++n > smax) break;
                }
                if (!got) { if (++fb > FB_CAP) useL2 = false; }
                else if (t > 0 && n > SLOW_N) { if (++slow > SLOW_CAP) useL2 = false; }
            }
            if (!got) {   // agent channel (baseline-proven delivery) — still store-free
                const unsigned long long* ha = hbA + (size_t)(t & 1) * 256 + lane * 4;
                for (;;) {
                    q0 = __hip_atomic_load(ha + 0, __ATOMIC_RELAXED, __HIP_MEMORY_SCOPE_AGENT);
                    q1 = __hip_atomic_load(ha + 1, __ATOMIC_RELAXED, __HIP_MEMORY_SCOPE_AGENT);
                    q2 = __hip_atomic_load(ha + 2, __ATOMIC_RELAXED, __HIP_MEMORY_SCOPE_AGENT);
                    q3 = __hip_atomic_load(ha + 3, __ATOMIC_RELAXED, __HIP_MEMORY_SCOPE_AGENT);
                    if (tags_ok(q0, q1, q2, q3, tt)) break;
                }
            }
            union { unsigned i; float f; } ua, ub, uc, ud;
            ua.i = (unsigned)q0; ub.i = (unsigned)q1; uc.i = (unsigned)q2; ud.i = (unsigned)q3;
            v4f hv; hv[0] = ua.f; hv[1] = ub.f; hv[2] = uc.f; hv[3] = ud.f;
            lds_h[t & 1][lane >> 4][lane & 15] = hv;
            __syncthreads();   // rendezvous: releases compute waves into step t
        }
    } else {
        // ================= COMPUTE WAVES 0..3 (R0-proven math; all stores live here) ==
        const int rl   = lane >> 2;         // 0..15
        const int kq   = lane & 3;          // k-quarter
        const int r_wg = wave * 16 + rl;    // local gate-row 0..63
        const int unit = w * 16 + (r_wg >> 2);     // global hidden unit
        const int gate = r_wg & 3;                 // 0=i 1=f 2=cell 3=o
        const int grow = gate * 256 + unit;        // global gate row 0..1023
        const int kbase = kq * 64;

        float whh[64], wih[64];
        {
            const float* p = Whh + (size_t)grow * 256 + kbase;
            #pragma unroll
            for (int j = 0; j < 64; j += 4) {
                float4 q = *(const float4*)(p + j);
                whh[j] = q.x; whh[j+1] = q.y; whh[j+2] = q.z; whh[j+3] = q.w;
            }
            p = Wih + (size_t)grow * 256 + kbase;
            #pragma unroll
            for (int j = 0; j < 64; j += 4) {
                float4 q = *(const float4*)(p + j);
                wih[j] = q.x; wih[j+1] = q.y; wih[j+2] = q.z; wih[j+3] = q.w;
            }
        }
        const float bias = bih[grow] + bhh[grow];
        const bool owner = ((lane & 15) == 0);
        const float act_scale = (gate == 2) ? 2.0f : 1.0f;
        const float act_off   = (gate == 2) ? 1.0f : 0.0f;

        v4f e_pipe;   // wave1's emb pipeline register (holds emb(t+1) at iter t top)
        if (wave == 1) {
            // stage emb(0) (plain load; compiler drains it before the LDS write)
            v4f e0 = *(const v4f*)(emb + (size_t)s_tok[0] * 256 + lane * 4);
            lds_e[0][lane >> 4][lane & 15] = e0;
            // issue emb(1) FIRST so iter0's vmcnt(2) leaves only the 2 init publishes flying
            ld_e4_issue(emb + (size_t)s_tok[1] * 256 + lane * 4, e_pipe);
        }
        if (owner) {   // publish h=0 tag0, parity0, both channels
            st_u64_sc0(hbL + unit, 0ull);
            __hip_atomic_store(hbA + unit, 0ull, __ATOMIC_RELAXED, __HIP_MEMORY_SCOPE_AGENT);
        }
        float c = 0.0f;
        __syncthreads();   // staging barrier (lds_e[0] visible; init publishes issued)

        for (int t = 0; t < T_STEPS; ++t) {
            // -- pre-barrier phase (overlaps the poller's discovery of h(t)) --
            if (wave == 1) {
                // e_pipe = emb(t+1), issued one iter ago. Counted wait: the 3 newest
                // ops are last iter's publishes (stores) -> vmcnt(3) never waits an ack.
                if (t == 0) { asm volatile("s_waitcnt vmcnt(2)" ::: "memory"); }
                else        { asm volatile("s_waitcnt vmcnt(3)" ::: "memory"); }
                __builtin_amdgcn_sched_barrier(0);
                asm volatile("" : "+v"(e_pipe));
                lds_e[(t + 1) & 1][lane >> 4][lane & 15] = e_pipe;   // safe: see race audit
                int nt = t + 2; if (nt > T_STEPS - 1) nt = T_STEPS - 1;
                ld_e4_issue(emb + (size_t)s_tok[nt] * 256 + lane * 4, e_pipe);
            }
            // wih . emb(t) — 4 independent chains
            float aA = 0.0f, aB = 0.0f, aC = 0.0f, aD = 0.0f;
            {
                const v4f* eb = &lds_e[t & 1][kq][0];
                #pragma unroll
                for (int i = 0; i < 16; i += 4) {
                    v4f v0 = eb[i], v1 = eb[i+1], v2 = eb[i+2], v3 = eb[i+3];
                    aA = fmaf(wih[4*i+ 0], v0[0], aA); aA = fmaf(wih[4*i+ 1], v0[1], aA);
                    aA = fmaf(wih[4*i+ 2], v0[2], aA); aA = fmaf(wih[4*i+ 3], v0[3], aA);
                    aB = fmaf(wih[4*i+ 4], v1[0], aB); aB = fmaf(wih[4*i+ 5], v1[1], aB);
                    aB = fmaf(wih[4*i+ 6], v1[2], aB); aB = fmaf(wih[4*i+ 7], v1[3], aB);
                    aC = fmaf(wih[4*i+ 8], v2[0], aC); aC = fmaf(wih[4*i+ 9], v2[1], aC);
                    aC = fmaf(wih[4*i+10], v2[2], aC); aC = fmaf(wih[4*i+11], v2[3], aC);
                    aD = fmaf(wih[4*i+12], v3[0], aD); aD = fmaf(wih[4*i+13], v3[1], aD);
                    aD = fmaf(wih[4*i+14], v3[2], aD); aD = fmaf(wih[4*i+15], v3[3], aD);
                }
            }
            __syncthreads();   // rendezvous: lds_h[t&1] holds h(t)
            // whh . h(t) — 4 independent chains
            {
                const v4f* hq = &lds_h[t & 1][kq][0];
                #pragma unroll
                for (int i = 0; i < 16; i += 4) {
                    v4f v0 = hq[i], v1 = hq[i+1], v2 = hq[i+2], v3 = hq[i+3];
                    aA = fmaf(whh[4*i+ 0], v0[0], aA); aA = fmaf(whh[4*i+ 1], v0[1], aA);
                    aA = fmaf(whh[4*i+ 2], v0[2], aA); aA = fmaf(whh[4*i+ 3], v0[3], aA);
                    aB = fmaf(whh[4*i+ 4], v1[0], aB); aB = fmaf(whh[4*i+ 5], v1[1], aB);
                    aB = fmaf(whh[4*i+ 6], v1[2], aB); aB = fmaf(whh[4*i+ 7], v1[3], aB);
                    aC = fmaf(whh[4*i+ 8], v2[0], aC); aC = fmaf(whh[4*i+ 9], v2[1], aC);
                    aC = fmaf(whh[4*i+10], v2[2], aC); aC = fmaf(whh[4*i+11], v2[3], aC);
                    aD = fmaf(whh[4*i+12], v3[0], aD); aD = fmaf(whh[4*i+13], v3[1], aD);
                    aD = fmaf(whh[4*i+14], v3[2], aD); aD = fmaf(whh[4*i+15], v3[3], aD);
                }
            }
            float acc = (aA + aB) + (aC + aD);
            acc += __shfl_xor(acc, 1, 64);
            acc += __shfl_xor(acc, 2, 64);
            acc += bias;
            float ex = __expf(-act_scale * acc);
            float av = act_scale / (1.0f + ex) - act_off;   // sigm gates 0/1/3, tanh gate 2
            const int base = lane & 48;
            float fv = __shfl(av, base + 4,  64);
            float gv = __shfl(av, base + 8,  64);
            float ov = __shfl(av, base + 12, 64);
            if (owner) {
                c = fmaf(fv, c, av * gv);
                float h = ov * tanh_fast(c);
                union { unsigned i; float f; } u; u.f = h;
                unsigned long long pk =
                    (((unsigned long long)(unsigned)(t + 1)) << 32) | (unsigned long long)u.i;
                const size_t so = (size_t)((t + 1) & 1) * 256 + unit;
                st_u64_sc0(hbL + so, pk);                                 // fast channel
                __hip_atomic_store(hbA + so, pk, __ATOMIC_RELAXED,
                                   __HIP_MEMORY_SCOPE_AGENT);             // fallback channel
                out[(size_t)t * HID + unit] = h;
                if (t == T_STEPS - 1) {
                    out[(size_t)T_STEPS * HID + unit]       = h;  // h_last
                    out[(size_t)T_STEPS * HID + HID + unit] = c;  // c_last
                }
            }
            // no producer drains: acks retire in the background; nothing in this wave
            // waits on them (wave1's counted vmcnt(3) explicitly excludes them).
        }
    }

    if (w == 0 && tid == 0) {
        // release the anti-DVFS spinners, then re-arm the election protocol
        __hip_atomic_store(ctl + 10, DONE_MAGIC, __ATOMIC_RELEASE, __HIP_MEMORY_SCOPE_AGENT);
        __hip_atomic_store(ctl + 0, 0u, __ATOMIC_RELAXED, __HIP_MEMORY_SCOPE_AGENT);
    }
}

extern "C" void kernel_launch(void* const* d_in, const int* in_sizes, int n_in,
                              void* d_out, int out_size, void* d_ws, size_t ws_size,
                              hipStream_t stream) {
    const int*   tokens = (const int*)d_in[0];
    const float* emb    = (const float*)d_in[1];
    const float* Wih    = (const float*)d_in[2];
    const float* Whh    = (const float*)d_in[3];
    const float* bih    = (const float*)d_in[4];
    const float* bhh    = (const float*)d_in[5];
    float* out = (float*)d_out;
    unsigned long long* hbL = (unsigned long long*)d_ws;                    // [2][256] u64
    unsigned long long* hbA = (unsigned long long*)((char*)d_ws + 4096);    // [2][256] u64
    unsigned* ctl = (unsigned*)((char*)d_ws + 8192);                        // election/done

    lstm_scan<<<NBLK, THREADS, 0, stream>>>(tokens, emb, Wih, Whh, bih, bhh, out, hbL, hbA, ctl);
}